// Round 1
// baseline (15055.728 us; speedup 1.0000x reference)
//
#include <hip/hip_runtime.h>
#include <hip/hip_bf16.h>

// LSTM trajectory predictor: 2-layer encoder (50 steps) + autoregressive
// 2-layer decoder (30 steps). B=2048, H=512, IN=5, OUT=2.
// Round 0: fp32 fused LSTM-cell kernel (GEMM + gates), correctness baseline.

#define HDIM 512
#define BDIM 2048
#define T_HIST 50
#define T_FUT 30

#define BM 64     // batch rows per block
#define BNH 32    // hidden units per block (z columns = 4*BNH = 128)
#define BK 16     // K chunk

// Fused LSTM cell:
//   z[m, g*H+n] = bias + sum_kx x[m,kx]*Wx[g*H+n,kx]
//                      + sum_k A1[m,k]*W1[g*H+n,k] (+ sum_k A2[m,k]*W2[g*H+n,k])
//   i,f,g,o gates -> c_new = f*c + i*g ; h_new = o*tanh(c_new)
// A2/W2 phase is used for layer-1 cells ([h0_new ; h1_prev] concat).
__global__ __launch_bounds__(256) void lstm_cell(
    const float* __restrict__ x, int x_stride, int Kx, const float* __restrict__ Wx,
    const float* __restrict__ A1, const float* __restrict__ W1,
    const float* __restrict__ A2, const float* __restrict__ W2,
    const float* __restrict__ b_ih, const float* __restrict__ b_hh,
    float* __restrict__ c_state, float* __restrict__ h_out)
{
    // LDS tiles, stored K-major. Ws columns are gate-interleaved: cc = u*4+g.
    __shared__ float As[BK][68];    // [k][m], padded
    __shared__ float Ws[BK][132];   // [k][cc], padded

    const int tid = threadIdx.x;
    const int tx = tid & 15;        // 0..15 -> hidden-unit pair (tx, tx+16)
    const int ty = tid >> 4;        // 0..15 -> row group (4 rows)
    const int n0 = blockIdx.x * BNH;
    const int m0 = blockIdx.y * BM;

    float acc[4][8];  // [r][uu*4+g], uu in {0,1}: units n0+tx, n0+tx+16

    // ---- bias init ----
    #pragma unroll
    for (int uu = 0; uu < 2; ++uu) {
        #pragma unroll
        for (int g = 0; g < 4; ++g) {
            int row = g * HDIM + n0 + tx + uu * 16;
            float b = b_ih[row] + b_hh[row];
            acc[0][uu*4+g] = b; acc[1][uu*4+g] = b;
            acc[2][uu*4+g] = b; acc[3][uu*4+g] = b;
        }
    }

    // ---- x prologue (tiny K: 5 for encoder, 2 for decoder; L2-cached) ----
    if (Kx > 0) {
        for (int kx = 0; kx < Kx; ++kx) {
            float w[8];
            #pragma unroll
            for (int uu = 0; uu < 2; ++uu)
                #pragma unroll
                for (int g = 0; g < 4; ++g)
                    w[uu*4+g] = Wx[(g * HDIM + n0 + tx + uu * 16) * Kx + kx];
            #pragma unroll
            for (int r = 0; r < 4; ++r) {
                float xv = x[(size_t)(m0 + ty * 4 + r) * x_stride + kx];
                #pragma unroll
                for (int c = 0; c < 8; ++c) acc[r][c] += xv * w[c];
            }
        }
    }

    // ---- main K phases (each K = 512, row stride 512 in A and W) ----
    for (int phase = 0; phase < 2; ++phase) {
        const float* A = phase ? A2 : A1;
        const float* W = phase ? W2 : W1;
        if (!A) break;
        for (int kc = 0; kc < HDIM; kc += BK) {
            __syncthreads();  // previous chunk's LDS reads done
            // stage A: 64 rows x 16 k, transposed into As[k][m]
            {
                int m = tid >> 2, k4 = tid & 3;
                float4 v = *(const float4*)&A[(size_t)(m0 + m) * HDIM + kc + k4 * 4];
                As[k4*4+0][m] = v.x; As[k4*4+1][m] = v.y;
                As[k4*4+2][m] = v.z; As[k4*4+3][m] = v.w;
            }
            // stage W: 128 gate-interleaved cols x 16 k into Ws[k][cc]
            #pragma unroll
            for (int it = 0; it < 2; ++it) {
                int cc = (tid >> 2) + it * 64;
                int u = cc >> 2, g = cc & 3;
                int k4 = tid & 3;
                float4 v = *(const float4*)&W[(size_t)(g * HDIM + n0 + u) * HDIM + kc + k4 * 4];
                Ws[k4*4+0][cc] = v.x; Ws[k4*4+1][cc] = v.y;
                Ws[k4*4+2][cc] = v.z; Ws[k4*4+3][cc] = v.w;
            }
            __syncthreads();
            #pragma unroll
            for (int kk = 0; kk < BK; ++kk) {
                float4 a  = *(const float4*)&As[kk][ty * 4];
                float4 w0 = *(const float4*)&Ws[kk][tx * 4];        // unit tx, gates 0..3
                float4 w1 = *(const float4*)&Ws[kk][64 + tx * 4];   // unit tx+16
                float av[4] = {a.x, a.y, a.z, a.w};
                float wv[8] = {w0.x, w0.y, w0.z, w0.w, w1.x, w1.y, w1.z, w1.w};
                #pragma unroll
                for (int r = 0; r < 4; ++r)
                    #pragma unroll
                    for (int c = 0; c < 8; ++c)
                        acc[r][c] += av[r] * wv[c];
            }
        }
    }

    // ---- gates + state update (each (m,n) owned by exactly one thread) ----
    #pragma unroll
    for (int uu = 0; uu < 2; ++uu) {
        int n = n0 + tx + uu * 16;
        #pragma unroll
        for (int r = 0; r < 4; ++r) {
            int m = m0 + ty * 4 + r;
            float zi = acc[r][uu*4+0], zf = acc[r][uu*4+1];
            float zg = acc[r][uu*4+2], zo = acc[r][uu*4+3];
            float ig = 1.f / (1.f + __expf(-zi));
            float fg = 1.f / (1.f + __expf(-zf));
            float gg = 2.f / (1.f + __expf(-2.f * zg)) - 1.f;   // tanh
            float og = 1.f / (1.f + __expf(-zo));
            size_t idx = (size_t)m * HDIM + n;
            float cn = fg * c_state[idx] + ig * gg;
            float hn = og * (2.f / (1.f + __expf(-2.f * cn)) - 1.f);
            c_state[idx] = cn;
            h_out[idx] = hn;
        }
    }
}

// Output head: pred = h1 @ out_W^T + out_b. One wave per batch row.
// Writes both d_out[m, t, :] and the feedback buffer xbuf[m, :].
__global__ __launch_bounds__(256) void head_kernel(
    const float* __restrict__ h1, const float* __restrict__ Wout,
    const float* __restrict__ bout, float* __restrict__ out,
    float* __restrict__ xbuf, int t)
{
    int wave = (blockIdx.x * 256 + threadIdx.x) >> 6;  // 0..2047
    int lane = threadIdx.x & 63;
    const float* hr = h1 + (size_t)wave * HDIM;
    float s0 = 0.f, s1 = 0.f;
    #pragma unroll
    for (int k = lane; k < HDIM; k += 64) {
        float hv = hr[k];
        s0 += hv * Wout[k];
        s1 += hv * Wout[HDIM + k];
    }
    #pragma unroll
    for (int off = 32; off > 0; off >>= 1) {
        s0 += __shfl_down(s0, off);
        s1 += __shfl_down(s1, off);
    }
    if (lane == 0) {
        float p0 = s0 + bout[0], p1 = s1 + bout[1];
        out[(size_t)wave * (T_FUT * 2) + t * 2 + 0] = p0;
        out[(size_t)wave * (T_FUT * 2) + t * 2 + 1] = p1;
        xbuf[wave * 2 + 0] = p0;
        xbuf[wave * 2 + 1] = p1;
    }
}

extern "C" void kernel_launch(void* const* d_in, const int* in_sizes, int n_in,
                              void* d_out, int out_size, void* d_ws, size_t ws_size,
                              hipStream_t stream) {
    const float* history = (const float*)d_in[0];
    // d_in[1] = future_frames (always 30 per setup)
    const float* eWih0 = (const float*)d_in[2];
    const float* eWhh0 = (const float*)d_in[3];
    const float* ebih0 = (const float*)d_in[4];
    const float* ebhh0 = (const float*)d_in[5];
    const float* eWih1 = (const float*)d_in[6];
    const float* eWhh1 = (const float*)d_in[7];
    const float* ebih1 = (const float*)d_in[8];
    const float* ebhh1 = (const float*)d_in[9];
    const float* dWih0 = (const float*)d_in[10];
    const float* dWhh0 = (const float*)d_in[11];
    const float* dbih0 = (const float*)d_in[12];
    const float* dbhh0 = (const float*)d_in[13];
    const float* dWih1 = (const float*)d_in[14];
    const float* dWhh1 = (const float*)d_in[15];
    const float* dbih1 = (const float*)d_in[16];
    const float* dbhh1 = (const float*)d_in[17];
    const float* outW  = (const float*)d_in[18];
    const float* outb  = (const float*)d_in[19];
    float* out = (float*)d_out;

    // workspace layout (floats): needs 6*B*H + 4096 floats ~= 24 MB
    float* ws  = (float*)d_ws;
    const size_t BH = (size_t)BDIM * HDIM;
    float* h0a = ws;
    float* h0b = ws + BH;
    float* h1a = ws + 2 * BH;
    float* h1b = ws + 3 * BH;
    float* c0  = ws + 4 * BH;
    float* c1  = ws + 5 * BH;   // c0,c1 contiguous
    float* xbuf = ws + 6 * BH;  // [B,2]

    // zero-init state every call (deterministic; graph-capture-safe)
    hipMemsetAsync(h0a, 0, BH * sizeof(float), stream);
    hipMemsetAsync(h1a, 0, BH * sizeof(float), stream);
    hipMemsetAsync(c0, 0, 2 * BH * sizeof(float), stream);
    hipMemsetAsync(xbuf, 0, BDIM * 2 * sizeof(float), stream);

    dim3 grid(HDIM / BNH, BDIM / BM);  // (16, 32) = 512 blocks
    dim3 blk(256);

    for (int s = 0; s < T_HIST + T_FUT; ++s) {
        float* h0r = (s & 1) ? h0b : h0a;
        float* h0w = (s & 1) ? h0a : h0b;
        float* h1r = (s & 1) ? h1b : h1a;
        float* h1w = (s & 1) ? h1a : h1b;
        if (s < T_HIST) {
            // encoder: x_t = history[:, s, :], row stride T_HIST*IN = 250
            lstm_cell<<<grid, blk, 0, stream>>>(
                history + s * 5, T_HIST * 5, 5, eWih0,
                h0r, eWhh0, nullptr, nullptr, ebih0, ebhh0, c0, h0w);
            lstm_cell<<<grid, blk, 0, stream>>>(
                nullptr, 0, 0, nullptr,
                h0w, eWih1, h1r, eWhh1, ebih1, ebhh1, c1, h1w);
        } else {
            lstm_cell<<<grid, blk, 0, stream>>>(
                xbuf, 2, 2, dWih0,
                h0r, dWhh0, nullptr, nullptr, dbih0, dbhh0, c0, h0w);
            lstm_cell<<<grid, blk, 0, stream>>>(
                nullptr, 0, 0, nullptr,
                h0w, dWih1, h1r, dWhh1, dbih1, dbhh1, c1, h1w);
            head_kernel<<<512, blk, 0, stream>>>(h1w, outW, outb, out, xbuf, s - T_HIST);
        }
    }
}

// Round 2
// 5343.447 us; speedup vs baseline: 2.8176x; 2.8176x over previous
//
#include <hip/hip_runtime.h>
#include <hip/hip_bf16.h>

// LSTM trajectory predictor, Round 1: bf16 hi/lo split MFMA cells.
// z = A@W^T via mfma_f32_16x16x32_bf16 with 3-product split (hi*hi + lo*hi + hi*lo).

#define HDIM 512
#define BDIM 2048
#define T_HIST 50
#define T_FUT 30

typedef __attribute__((ext_vector_type(8))) short short8;
typedef __attribute__((ext_vector_type(4))) float f32x4;

__device__ __forceinline__ ushort f2bf(float f) {
    union { float f; unsigned u; } v; v.f = f;
    unsigned r = v.u + 0x7fff + ((v.u >> 16) & 1);   // RNE
    return (ushort)(r >> 16);
}
__device__ __forceinline__ float bf2f(ushort h) {
    union { unsigned u; float f; } v; v.u = ((unsigned)h) << 16;
    return v.f;
}

// ---- weight prep: fp32 [2048][512] -> bf16 hi/lo [2048][512], rows permuted.
// input row = g*512 + u ; output row rp = (u>>5)*128 + ((u>>4)&1)*64 + g*16 + (u&15)
// so a block's 128 rows = 32 units x 4 gates, and a wave's 4 n-fragments = 4 gates.
struct SplitSrc { const float* src[6]; };

__global__ __launch_bounds__(256) void split_weights(SplitSrc s, ushort* __restrict__ hi,
                                                     ushort* __restrict__ lo) {
    int row = blockIdx.x;             // g*512 + u
    int j = blockIdx.y;               // matrix index
    int g = row >> 9, u = row & 511;
    int rp = (u >> 5) * 128 + ((u >> 4) & 1) * 64 + g * 16 + (u & 15);
    const float* S = s.src[j] + (size_t)row * HDIM;
    ushort* H = hi + ((size_t)j * 2048 + rp) * HDIM;
    ushort* L = lo + ((size_t)j * 2048 + rp) * HDIM;
    for (int k = threadIdx.x; k < HDIM; k += 256) {
        float w = S[k];
        ushort hb = f2bf(w);
        H[k] = hb;
        L[k] = f2bf(w - bf2f(hb));
    }
}

// ---- fused LSTM cell, MFMA version ----
// Tile: BM=64 (batch rows) x BN=128 (permuted z cols = 32 units x 4 gates), BK=64.
// 4 waves: wm = w>>1 (m half), wn = w&1 (16-unit half). Wave = 32x64 out =
// 2 m-frags x 4 n-frags(=gates) of 16x16.
// K phases: np super-phases (A,W pairs), each split into 3 bf16 sub-phases.
__global__ __launch_bounds__(256) void lstm_cell_mfma(
    const ushort* __restrict__ A1hi, const ushort* __restrict__ A1lo,
    const ushort* __restrict__ W1hi, const ushort* __restrict__ W1lo,
    const ushort* __restrict__ A2hi, const ushort* __restrict__ A2lo,
    const ushort* __restrict__ W2hi, const ushort* __restrict__ W2lo,
    int np,
    const float* __restrict__ x, int x_stride, int Kx, const float* __restrict__ Wx,
    const float* __restrict__ bih, const float* __restrict__ bhh,
    float* __restrict__ c_state, ushort* __restrict__ h_hi, ushort* __restrict__ h_lo)
{
    // 16B slots; slot_phys = slot_log ^ (row&7)  (XOR swizzle, 2-way max on reads)
    __shared__ __align__(16) ushort Asub[64 * 64];    // 8 KB
    __shared__ __align__(16) ushort Bsub[128 * 64];   // 16 KB

    const int tid = threadIdx.x;
    const int w = tid >> 6, l = tid & 63;
    const int wm = w >> 1, wn = w & 1;
    const int m0 = blockIdx.y * 64;
    const int n0 = blockIdx.x * 128;                        // permuted W row base
    const int u  = blockIdx.x * 32 + wn * 16 + (l & 15);    // global hidden unit
    const int lrow = l & 15, lk = l >> 4;

    f32x4 acc[2][4];   // [m-frag][gate]

    // bias init (same bias for all 4 rows of a reg quad)
    #pragma unroll
    for (int g = 0; g < 4; ++g) {
        float b = bih[g * HDIM + u] + bhh[g * HDIM + u];
        f32x4 bv = {b, b, b, b};
        acc[0][g] = bv; acc[1][g] = bv;
    }

    // tiny-K x contribution in fp32 (K=5 encoder / K=2 decoder)
    if (Kx > 0) {
        for (int kx = 0; kx < Kx; ++kx) {
            float wv[4];
            #pragma unroll
            for (int g = 0; g < 4; ++g) wv[g] = Wx[(size_t)(g * HDIM + u) * Kx + kx];
            #pragma unroll
            for (int fm = 0; fm < 2; ++fm)
                #pragma unroll
                for (int r = 0; r < 4; ++r) {
                    int m = m0 + wm * 32 + fm * 16 + lk * 4 + r;
                    float xv = x[(size_t)m * x_stride + kx];
                    #pragma unroll
                    for (int g = 0; g < 4; ++g) acc[fm][g][r] += xv * wv[g];
                }
        }
    }

    for (int p = 0; p < np; ++p) {
        const ushort* Ahi = p ? A2hi : A1hi;
        const ushort* Alo = p ? A2lo : A1lo;
        const ushort* Whi = p ? W2hi : W1hi;
        const ushort* Wlo = p ? W2lo : W1lo;
        #pragma unroll 1
        for (int sp3 = 0; sp3 < 3; ++sp3) {
            const ushort* Ap = (sp3 == 1) ? Alo : Ahi;   // hi, lo, hi
            const ushort* Wp = (sp3 == 2) ? Wlo : Whi;   // hi, hi, lo
            #pragma unroll 1
            for (int kc = 0; kc < HDIM; kc += 64) {
                __syncthreads();   // previous chunk's LDS reads complete
                // stage A: 512 slots of 16B, linear LDS dest, pre-swizzled source
                #pragma unroll
                for (int it = 0; it < 2; ++it) {
                    int base = (w * 2 + it) * 64;
                    int L = base + l;
                    int row = L >> 3, spx = L & 7;
                    int slog = spx ^ (row & 7);
                    const ushort* gp = Ap + (size_t)(m0 + row) * HDIM + kc + slog * 8;
                    __builtin_amdgcn_global_load_lds(
                        (const __attribute__((address_space(1))) void*)gp,
                        (__attribute__((address_space(3))) void*)&Asub[base * 8],
                        16, 0, 0);
                }
                // stage B: 1024 slots
                #pragma unroll
                for (int it = 0; it < 4; ++it) {
                    int base = (w * 4 + it) * 64;
                    int L = base + l;
                    int row = L >> 3, spx = L & 7;
                    int slog = spx ^ (row & 7);
                    const ushort* gp = Wp + (size_t)(n0 + row) * HDIM + kc + slog * 8;
                    __builtin_amdgcn_global_load_lds(
                        (const __attribute__((address_space(1))) void*)gp,
                        (__attribute__((address_space(3))) void*)&Bsub[base * 8],
                        16, 0, 0);
                }
                __syncthreads();   // staging visible (compiler drains vmcnt)
                #pragma unroll
                for (int ks = 0; ks < 2; ++ks) {
                    short8 af[2], bfr[4];
                    #pragma unroll
                    for (int fm = 0; fm < 2; ++fm) {
                        int row = wm * 32 + fm * 16 + lrow;
                        int spx = (ks * 4 + lk) ^ (row & 7);
                        af[fm] = *(const short8*)&Asub[(row * 8 + spx) * 8];
                    }
                    #pragma unroll
                    for (int g = 0; g < 4; ++g) {
                        int row = wn * 64 + g * 16 + lrow;
                        int spx = (ks * 4 + lk) ^ (row & 7);
                        bfr[g] = *(const short8*)&Bsub[(row * 8 + spx) * 8];
                    }
                    #pragma unroll
                    for (int fm = 0; fm < 2; ++fm)
                        #pragma unroll
                        for (int g = 0; g < 4; ++g)
                            acc[fm][g] = __builtin_amdgcn_mfma_f32_16x16x32_bf16(
                                af[fm], bfr[g], acc[fm][g], 0, 0, 0);
                }
            }
        }
    }

    // epilogue: gates + state update. Thread owns (8 rows m) x (1 unit u).
    #pragma unroll
    for (int fm = 0; fm < 2; ++fm)
        #pragma unroll
        for (int r = 0; r < 4; ++r) {
            int m = m0 + wm * 32 + fm * 16 + lk * 4 + r;
            size_t idx = (size_t)m * HDIM + u;
            float zi = acc[fm][0][r], zf = acc[fm][1][r];
            float zg = acc[fm][2][r], zo = acc[fm][3][r];
            float ig = 1.f / (1.f + __expf(-zi));
            float fg = 1.f / (1.f + __expf(-zf));
            float gg = 2.f / (1.f + __expf(-2.f * zg)) - 1.f;
            float og = 1.f / (1.f + __expf(-zo));
            float cn = fg * c_state[idx] + ig * gg;
            float hn = og * (2.f / (1.f + __expf(-2.f * cn)) - 1.f);
            c_state[idx] = cn;
            ushort hb = f2bf(hn);
            h_hi[idx] = hb;
            h_lo[idx] = f2bf(hn - bf2f(hb));
        }
}

// ---- output head: pred = (h_hi+h_lo) @ out_W^T + out_b, one wave per row ----
__global__ __launch_bounds__(256) void head_kernel(
    const ushort* __restrict__ hhi, const ushort* __restrict__ hlo,
    const float* __restrict__ Wout, const float* __restrict__ bout,
    float* __restrict__ out, float* __restrict__ xbuf, int t)
{
    int wave = (blockIdx.x * 256 + threadIdx.x) >> 6;
    int lane = threadIdx.x & 63;
    const ushort* hr = hhi + (size_t)wave * HDIM;
    const ushort* lr = hlo + (size_t)wave * HDIM;
    float s0 = 0.f, s1 = 0.f;
    #pragma unroll
    for (int k = lane; k < HDIM; k += 64) {
        float hv = bf2f(hr[k]) + bf2f(lr[k]);
        s0 += hv * Wout[k];
        s1 += hv * Wout[HDIM + k];
    }
    #pragma unroll
    for (int off = 32; off > 0; off >>= 1) {
        s0 += __shfl_down(s0, off);
        s1 += __shfl_down(s1, off);
    }
    if (lane == 0) {
        float p0 = s0 + bout[0], p1 = s1 + bout[1];
        out[(size_t)wave * (T_FUT * 2) + t * 2 + 0] = p0;
        out[(size_t)wave * (T_FUT * 2) + t * 2 + 1] = p1;
        xbuf[wave * 2 + 0] = p0;
        xbuf[wave * 2 + 1] = p1;
    }
}

extern "C" void kernel_launch(void* const* d_in, const int* in_sizes, int n_in,
                              void* d_out, int out_size, void* d_ws, size_t ws_size,
                              hipStream_t stream) {
    const float* history = (const float*)d_in[0];
    const float* eWih0 = (const float*)d_in[2];
    const float* eWhh0 = (const float*)d_in[3];
    const float* ebih0 = (const float*)d_in[4];
    const float* ebhh0 = (const float*)d_in[5];
    const float* eWih1 = (const float*)d_in[6];
    const float* eWhh1 = (const float*)d_in[7];
    const float* ebih1 = (const float*)d_in[8];
    const float* ebhh1 = (const float*)d_in[9];
    const float* dWih0 = (const float*)d_in[10];
    const float* dWhh0 = (const float*)d_in[11];
    const float* dbih0 = (const float*)d_in[12];
    const float* dbhh0 = (const float*)d_in[13];
    const float* dWih1 = (const float*)d_in[14];
    const float* dWhh1 = (const float*)d_in[15];
    const float* dbih1 = (const float*)d_in[16];
    const float* dbhh1 = (const float*)d_in[17];
    const float* outW  = (const float*)d_in[18];
    const float* outb  = (const float*)d_in[19];
    float* out = (float*)d_out;

    // ---- workspace layout ----
    const size_t M = (size_t)2048 * 512;   // elems per [2048][512] matrix
    ushort* whi = (ushort*)d_ws;           // 6 split-hi weight matrices
    ushort* wlo = whi + 6 * M;             // 6 split-lo
    ushort* hb  = wlo + 6 * M;             // 8 h buffers (hi/lo x 2 layers x dbuf)
    float*  c0  = (float*)(hb + 8 * M);
    float*  c1  = c0 + M;
    float*  xbuf = c1 + M;                 // [B,2] decoder feedback

    ushort* h0a_hi = hb + 0 * M; ushort* h0a_lo = hb + 1 * M;
    ushort* h0b_hi = hb + 2 * M; ushort* h0b_lo = hb + 3 * M;
    ushort* h1a_hi = hb + 4 * M; ushort* h1a_lo = hb + 5 * M;
    ushort* h1b_hi = hb + 6 * M; ushort* h1b_lo = hb + 7 * M;

    // zero-init state each call (deterministic, graph-capture-safe)
    hipMemsetAsync(h0a_hi, 0, 2 * M * sizeof(ushort), stream);  // h0a hi+lo
    hipMemsetAsync(h1a_hi, 0, 2 * M * sizeof(ushort), stream);  // h1a hi+lo
    hipMemsetAsync(c0, 0, 2 * M * sizeof(float), stream);       // c0+c1
    hipMemsetAsync(xbuf, 0, BDIM * 2 * sizeof(float), stream);

    // ---- split+permute the 6 big weight matrices ----
    SplitSrc ss;
    ss.src[0] = eWhh0; ss.src[1] = eWih1; ss.src[2] = eWhh1;
    ss.src[3] = dWhh0; ss.src[4] = dWih1; ss.src[5] = dWhh1;
    split_weights<<<dim3(2048, 6), 256, 0, stream>>>(ss, whi, wlo);

    #define WHI(j) (whi + (size_t)(j) * M)
    #define WLO(j) (wlo + (size_t)(j) * M)

    dim3 cgrid(16, 32);   // (N/128, B/64) = 512 blocks
    dim3 blk(256);

    for (int s = 0; s < T_HIST + T_FUT; ++s) {
        ushort* h0r_hi = (s & 1) ? h0b_hi : h0a_hi;
        ushort* h0r_lo = (s & 1) ? h0b_lo : h0a_lo;
        ushort* h0w_hi = (s & 1) ? h0a_hi : h0b_hi;
        ushort* h0w_lo = (s & 1) ? h0a_lo : h0b_lo;
        ushort* h1r_hi = (s & 1) ? h1b_hi : h1a_hi;
        ushort* h1r_lo = (s & 1) ? h1b_lo : h1a_lo;
        ushort* h1w_hi = (s & 1) ? h1a_hi : h1b_hi;
        ushort* h1w_lo = (s & 1) ? h1a_lo : h1b_lo;

        if (s < T_HIST) {
            lstm_cell_mfma<<<cgrid, blk, 0, stream>>>(
                h0r_hi, h0r_lo, WHI(0), WLO(0),
                nullptr, nullptr, nullptr, nullptr, 1,
                history + s * 5, T_HIST * 5, 5, eWih0,
                ebih0, ebhh0, c0, h0w_hi, h0w_lo);
            lstm_cell_mfma<<<cgrid, blk, 0, stream>>>(
                h0w_hi, h0w_lo, WHI(1), WLO(1),
                h1r_hi, h1r_lo, WHI(2), WLO(2), 2,
                nullptr, 0, 0, nullptr,
                ebih1, ebhh1, c1, h1w_hi, h1w_lo);
        } else {
            lstm_cell_mfma<<<cgrid, blk, 0, stream>>>(
                h0r_hi, h0r_lo, WHI(3), WLO(3),
                nullptr, nullptr, nullptr, nullptr, 1,
                xbuf, 2, 2, dWih0,
                dbih0, dbhh0, c0, h0w_hi, h0w_lo);
            lstm_cell_mfma<<<cgrid, blk, 0, stream>>>(
                h0w_hi, h0w_lo, WHI(4), WLO(4),
                h1r_hi, h1r_lo, WHI(5), WLO(5), 2,
                nullptr, 0, 0, nullptr,
                dbih1, dbhh1, c1, h1w_hi, h1w_lo);
            head_kernel<<<512, blk, 0, stream>>>(h1w_hi, h1w_lo, outW, outb,
                                                 out, xbuf, s - T_HIST);
        }
    }
    #undef WHI
    #undef WLO
}

// Round 3
// 3966.258 us; speedup vs baseline: 3.7960x; 1.3472x over previous
//
#include <hip/hip_runtime.h>
#include <hip/hip_bf16.h>

// LSTM trajectory predictor, Round 2: fused hi/lo staging, 128x128 block tile,
// 64x64 wave tiles, double-buffered LDS, XCD-chunked block swizzle.

#define HDIM 512
#define BDIM 2048
#define T_HIST 50
#define T_FUT 30

typedef __attribute__((ext_vector_type(8))) short short8;
typedef __attribute__((ext_vector_type(4))) float f32x4;

#define AS1(p) ((const __attribute__((address_space(1))) void*)(p))
#define AS3(p) ((__attribute__((address_space(3))) void*)(p))

__device__ __forceinline__ ushort f2bf(float f) {
    union { float f; unsigned u; } v; v.f = f;
    unsigned r = v.u + 0x7fff + ((v.u >> 16) & 1);   // RNE
    return (ushort)(r >> 16);
}
__device__ __forceinline__ float bf2f(ushort h) {
    union { unsigned u; float f; } v; v.u = ((unsigned)h) << 16;
    return v.f;
}

// ---- weight prep: fp32 [2048][512] -> bf16 hi/lo [2048][512], rows permuted.
// input row = g*512 + u ; output row rp = (u>>5)*128 + ((u>>4)&1)*64 + g*16 + (u&15)
struct SplitSrc { const float* src[6]; };

__global__ __launch_bounds__(256) void split_weights(SplitSrc s, ushort* __restrict__ hi,
                                                     ushort* __restrict__ lo) {
    int row = blockIdx.x;             // g*512 + u
    int j = blockIdx.y;               // matrix index
    int g = row >> 9, u = row & 511;
    int rp = (u >> 5) * 128 + ((u >> 4) & 1) * 64 + g * 16 + (u & 15);
    const float* S = s.src[j] + (size_t)row * HDIM;
    ushort* H = hi + ((size_t)j * 2048 + rp) * HDIM;
    ushort* L = lo + ((size_t)j * 2048 + rp) * HDIM;
    for (int k = threadIdx.x; k < HDIM; k += 256) {
        float w = S[k];
        ushort hb = f2bf(w);
        H[k] = hb;
        L[k] = f2bf(w - bf2f(hb));
    }
}

// ---- fused LSTM cell ----
// Block tile: 128 (batch rows) x 128 (permuted z cols = 32 units x 4 gates).
// 4 waves in 2x2: wave tile 64x64 = 4 m-frags x 4 gate-frags of 16x16.
// Per K-chunk (BK=64): stage A_hi/A_lo/B_hi/B_lo once, run 3 MFMA products.
// Double-buffered LDS, one barrier per chunk, staging overlaps compute.
__global__ __launch_bounds__(256) void lstm_cell_mfma(
    const ushort* __restrict__ A1hi, const ushort* __restrict__ A1lo,
    const ushort* __restrict__ W1hi, const ushort* __restrict__ W1lo,
    const ushort* __restrict__ A2hi, const ushort* __restrict__ A2lo,
    const ushort* __restrict__ W2hi, const ushort* __restrict__ W2lo,
    int np,
    const float* __restrict__ x, int x_stride, int Kx, const float* __restrict__ Wx,
    const float* __restrict__ bih, const float* __restrict__ bhh,
    float* __restrict__ c_state, ushort* __restrict__ h_hi, ushort* __restrict__ h_lo)
{
    // per buffer (ushort offsets): A_hi 0, A_lo 8192, B_hi 16384, B_lo 24576
    // each region: 128 rows x 64 k (1024 slots of 16B), XOR-swizzled slots.
    __shared__ __align__(16) ushort lds[2][32768];   // 2 x 64 KB

    const int tid = threadIdx.x;
    const int w = tid >> 6, l = tid & 63;
    const int wm = w >> 1, wn = w & 1;
    const int lrow = l & 15, lk = l >> 4;

    // XCD-chunked bijective swizzle: XCD gets 4 bx x 8 by (weights L2-stable)
    int id = blockIdx.y * 16 + blockIdx.x;
    int xcd = id & 7, rr = id >> 3;
    int bx = (xcd & 3) * 4 + (rr & 3);
    int by = (xcd >> 2) * 8 + (rr >> 2);
    const int m0 = by * 128;
    const int n0 = bx * 128;
    const int u  = bx * 32 + wn * 16 + lrow;   // global hidden unit

    f32x4 acc[4][4];   // [m-frag][gate]

    // ---- prologue staging of chunk 0 (get loads in flight first) ----
    auto STAGE = [&](int buf, int t) {
        int p = t >> 3;
        int kc = (t & 7) * 64;
        const ushort* Ah = p ? A2hi : A1hi;
        const ushort* Al = p ? A2lo : A1lo;
        const ushort* Bh = p ? W2hi : W1hi;
        const ushort* Bl = p ? W2lo : W1lo;
        ushort* base = &lds[buf][0];
        #pragma unroll
        for (int it = 0; it < 4; ++it) {
            int sb = (w * 4 + it) * 64;     // wave-uniform slot base
            int slot = sb + l;
            int row = slot >> 3;
            int spx = (slot & 7) ^ (row & 7);
            size_t go = (size_t)row * HDIM + kc + spx * 8;
            __builtin_amdgcn_global_load_lds(AS1(Ah + (size_t)m0 * HDIM + go),
                                             AS3(base + sb * 8), 16, 0, 0);
            __builtin_amdgcn_global_load_lds(AS1(Al + (size_t)m0 * HDIM + go),
                                             AS3(base + 8192 + sb * 8), 16, 0, 0);
            __builtin_amdgcn_global_load_lds(AS1(Bh + (size_t)n0 * HDIM + go),
                                             AS3(base + 16384 + sb * 8), 16, 0, 0);
            __builtin_amdgcn_global_load_lds(AS1(Bl + (size_t)n0 * HDIM + go),
                                             AS3(base + 24576 + sb * 8), 16, 0, 0);
        }
    };

    STAGE(0, 0);

    // ---- bias init (overlaps staging latency) ----
    #pragma unroll
    for (int g = 0; g < 4; ++g) {
        float b = bih[g * HDIM + u] + bhh[g * HDIM + u];
        f32x4 bv = {b, b, b, b};
        #pragma unroll
        for (int fm = 0; fm < 4; ++fm) acc[fm][g] = bv;
    }

    // ---- tiny-K x contribution in fp32 (K=5 encoder / K=2 decoder) ----
    if (Kx > 0) {
        for (int kx = 0; kx < Kx; ++kx) {
            float wv[4];
            #pragma unroll
            for (int g = 0; g < 4; ++g) wv[g] = Wx[(size_t)(g * HDIM + u) * Kx + kx];
            #pragma unroll
            for (int fm = 0; fm < 4; ++fm)
                #pragma unroll
                for (int r = 0; r < 4; ++r) {
                    int m = m0 + wm * 64 + fm * 16 + lk * 4 + r;
                    float xv = x[(size_t)m * x_stride + kx];
                    #pragma unroll
                    for (int g = 0; g < 4; ++g) acc[fm][g][r] += xv * wv[g];
                }
        }
    }

    // ---- main loop: one barrier per chunk, stage t+1 while computing t ----
    const int nch = np * 8;
    for (int t = 0; t < nch; ++t) {
        int cur = t & 1;
        __syncthreads();              // drains vmcnt: buf[cur] staging complete
        if (t + 1 < nch) STAGE(cur ^ 1, t + 1);
        ushort* base = &lds[cur][0];
        #pragma unroll
        for (int ks = 0; ks < 2; ++ks) {
            short8 ah[4], al[4], bh[4], bl[4];
            #pragma unroll
            for (int fm = 0; fm < 4; ++fm) {
                int row = wm * 64 + fm * 16 + lrow;
                int spx = (ks * 4 + lk) ^ (row & 7);
                int off = (row * 8 + spx) * 8;
                ah[fm] = *(const short8*)(base + off);
                al[fm] = *(const short8*)(base + 8192 + off);
            }
            #pragma unroll
            for (int g = 0; g < 4; ++g) {
                int row = wn * 64 + g * 16 + lrow;
                int spx = (ks * 4 + lk) ^ (row & 7);
                int off = (row * 8 + spx) * 8;
                bh[g] = *(const short8*)(base + 16384 + off);
                bl[g] = *(const short8*)(base + 24576 + off);
            }
            #pragma unroll
            for (int fm = 0; fm < 4; ++fm)
                #pragma unroll
                for (int g = 0; g < 4; ++g)
                    acc[fm][g] = __builtin_amdgcn_mfma_f32_16x16x32_bf16(
                        ah[fm], bh[g], acc[fm][g], 0, 0, 0);
            #pragma unroll
            for (int fm = 0; fm < 4; ++fm)
                #pragma unroll
                for (int g = 0; g < 4; ++g)
                    acc[fm][g] = __builtin_amdgcn_mfma_f32_16x16x32_bf16(
                        al[fm], bh[g], acc[fm][g], 0, 0, 0);
            #pragma unroll
            for (int fm = 0; fm < 4; ++fm)
                #pragma unroll
                for (int g = 0; g < 4; ++g)
                    acc[fm][g] = __builtin_amdgcn_mfma_f32_16x16x32_bf16(
                        ah[fm], bl[g], acc[fm][g], 0, 0, 0);
        }
    }

    // ---- epilogue: gates + state update. Thread owns 16 rows x 1 unit. ----
    #pragma unroll
    for (int fm = 0; fm < 4; ++fm)
        #pragma unroll
        for (int r = 0; r < 4; ++r) {
            int m = m0 + wm * 64 + fm * 16 + lk * 4 + r;
            size_t idx = (size_t)m * HDIM + u;
            float zi = acc[fm][0][r], zf = acc[fm][1][r];
            float zg = acc[fm][2][r], zo = acc[fm][3][r];
            float ig = 1.f / (1.f + __expf(-zi));
            float fg = 1.f / (1.f + __expf(-zf));
            float gg = 2.f / (1.f + __expf(-2.f * zg)) - 1.f;
            float og = 1.f / (1.f + __expf(-zo));
            float cn = fg * c_state[idx] + ig * gg;
            float hn = og * (2.f / (1.f + __expf(-2.f * cn)) - 1.f);
            c_state[idx] = cn;
            ushort hb = f2bf(hn);
            h_hi[idx] = hb;
            h_lo[idx] = f2bf(hn - bf2f(hb));
        }
}

// ---- output head: pred = (h_hi+h_lo) @ out_W^T + out_b, one wave per row ----
__global__ __launch_bounds__(256) void head_kernel(
    const ushort* __restrict__ hhi, const ushort* __restrict__ hlo,
    const float* __restrict__ Wout, const float* __restrict__ bout,
    float* __restrict__ out, float* __restrict__ xbuf, int t)
{
    int wave = (blockIdx.x * 256 + threadIdx.x) >> 6;
    int lane = threadIdx.x & 63;
    const ushort* hr = hhi + (size_t)wave * HDIM;
    const ushort* lr = hlo + (size_t)wave * HDIM;
    float s0 = 0.f, s1 = 0.f;
    #pragma unroll
    for (int k = lane; k < HDIM; k += 64) {
        float hv = bf2f(hr[k]) + bf2f(lr[k]);
        s0 += hv * Wout[k];
        s1 += hv * Wout[HDIM + k];
    }
    #pragma unroll
    for (int off = 32; off > 0; off >>= 1) {
        s0 += __shfl_down(s0, off);
        s1 += __shfl_down(s1, off);
    }
    if (lane == 0) {
        float p0 = s0 + bout[0], p1 = s1 + bout[1];
        out[(size_t)wave * (T_FUT * 2) + t * 2 + 0] = p0;
        out[(size_t)wave * (T_FUT * 2) + t * 2 + 1] = p1;
        xbuf[wave * 2 + 0] = p0;
        xbuf[wave * 2 + 1] = p1;
    }
}

extern "C" void kernel_launch(void* const* d_in, const int* in_sizes, int n_in,
                              void* d_out, int out_size, void* d_ws, size_t ws_size,
                              hipStream_t stream) {
    const float* history = (const float*)d_in[0];
    const float* eWih0 = (const float*)d_in[2];
    const float* eWhh0 = (const float*)d_in[3];
    const float* ebih0 = (const float*)d_in[4];
    const float* ebhh0 = (const float*)d_in[5];
    const float* eWih1 = (const float*)d_in[6];
    const float* eWhh1 = (const float*)d_in[7];
    const float* ebih1 = (const float*)d_in[8];
    const float* ebhh1 = (const float*)d_in[9];
    const float* dWih0 = (const float*)d_in[10];
    const float* dWhh0 = (const float*)d_in[11];
    const float* dbih0 = (const float*)d_in[12];
    const float* dbhh0 = (const float*)d_in[13];
    const float* dWih1 = (const float*)d_in[14];
    const float* dWhh1 = (const float*)d_in[15];
    const float* dbih1 = (const float*)d_in[16];
    const float* dbhh1 = (const float*)d_in[17];
    const float* outW  = (const float*)d_in[18];
    const float* outb  = (const float*)d_in[19];
    float* out = (float*)d_out;

    // ---- workspace layout ----
    const size_t M = (size_t)2048 * 512;
    ushort* whi = (ushort*)d_ws;           // 6 split-hi weight matrices
    ushort* wlo = whi + 6 * M;             // 6 split-lo
    ushort* hb  = wlo + 6 * M;             // 8 h buffers (hi/lo x 2 layers x dbuf)
    float*  c0  = (float*)(hb + 8 * M);
    float*  c1  = c0 + M;
    float*  xbuf = c1 + M;                 // [B,2] decoder feedback

    ushort* h0a_hi = hb + 0 * M; ushort* h0a_lo = hb + 1 * M;
    ushort* h0b_hi = hb + 2 * M; ushort* h0b_lo = hb + 3 * M;
    ushort* h1a_hi = hb + 4 * M; ushort* h1a_lo = hb + 5 * M;
    ushort* h1b_hi = hb + 6 * M; ushort* h1b_lo = hb + 7 * M;

    hipMemsetAsync(h0a_hi, 0, 2 * M * sizeof(ushort), stream);
    hipMemsetAsync(h1a_hi, 0, 2 * M * sizeof(ushort), stream);
    hipMemsetAsync(c0, 0, 2 * M * sizeof(float), stream);
    hipMemsetAsync(xbuf, 0, BDIM * 2 * sizeof(float), stream);

    SplitSrc ss;
    ss.src[0] = eWhh0; ss.src[1] = eWih1; ss.src[2] = eWhh1;
    ss.src[3] = dWhh0; ss.src[4] = dWih1; ss.src[5] = dWhh1;
    split_weights<<<dim3(2048, 6), 256, 0, stream>>>(ss, whi, wlo);

    #define WHI(j) (whi + (size_t)(j) * M)
    #define WLO(j) (wlo + (size_t)(j) * M)

    dim3 cgrid(16, 16);   // (N/128, B/128) = 256 blocks = 1/CU
    dim3 blk(256);

    for (int s = 0; s < T_HIST + T_FUT; ++s) {
        ushort* h0r_hi = (s & 1) ? h0b_hi : h0a_hi;
        ushort* h0r_lo = (s & 1) ? h0b_lo : h0a_lo;
        ushort* h0w_hi = (s & 1) ? h0a_hi : h0b_hi;
        ushort* h0w_lo = (s & 1) ? h0a_lo : h0b_lo;
        ushort* h1r_hi = (s & 1) ? h1b_hi : h1a_hi;
        ushort* h1r_lo = (s & 1) ? h1b_lo : h1a_lo;
        ushort* h1w_hi = (s & 1) ? h1a_hi : h1b_hi;
        ushort* h1w_lo = (s & 1) ? h1a_lo : h1b_lo;

        if (s < T_HIST) {
            lstm_cell_mfma<<<cgrid, blk, 0, stream>>>(
                h0r_hi, h0r_lo, WHI(0), WLO(0),
                nullptr, nullptr, nullptr, nullptr, 1,
                history + s * 5, T_HIST * 5, 5, eWih0,
                ebih0, ebhh0, c0, h0w_hi, h0w_lo);
            lstm_cell_mfma<<<cgrid, blk, 0, stream>>>(
                h0w_hi, h0w_lo, WHI(1), WLO(1),
                h1r_hi, h1r_lo, WHI(2), WLO(2), 2,
                nullptr, 0, 0, nullptr,
                ebih1, ebhh1, c1, h1w_hi, h1w_lo);
        } else {
            lstm_cell_mfma<<<cgrid, blk, 0, stream>>>(
                h0r_hi, h0r_lo, WHI(3), WLO(3),
                nullptr, nullptr, nullptr, nullptr, 1,
                xbuf, 2, 2, dWih0,
                dbih0, dbhh0, c0, h0w_hi, h0w_lo);
            lstm_cell_mfma<<<cgrid, blk, 0, stream>>>(
                h0w_hi, h0w_lo, WHI(4), WLO(4),
                h1r_hi, h1r_lo, WHI(5), WLO(5), 2,
                nullptr, 0, 0, nullptr,
                dbih1, dbhh1, c1, h1w_hi, h1w_lo);
            head_kernel<<<512, blk, 0, stream>>>(h1w_hi, h1w_lo, outW, outb,
                                                 out, xbuf, s - T_HIST);
        }
    }
    #undef WHI
    #undef WLO
}